// Round 20
// baseline (359.429 us; speedup 1.0000x reference)
//
#include <hip/hip_runtime.h>
#include <hip/hip_bf16.h>
#include <cstdint>
#include <cstddef>

#define NEG_SLOPE 0.2f

typedef short short8 __attribute__((ext_vector_type(8)));
typedef float f32x4 __attribute__((ext_vector_type(4)));
typedef unsigned short ushort4v __attribute__((ext_vector_type(4)));
typedef unsigned short ushort8v __attribute__((ext_vector_type(8)));

__device__ __forceinline__ float lrelu(float x){ return x > 0.f ? x : NEG_SLOPE * x; }
__device__ __forceinline__ float eluf(float x){ return x > 0.f ? x : __expf(x) - 1.f; }

__device__ __forceinline__ unsigned short f2bf(float f){
  union { float f; unsigned int u; } v; v.f = f;
  unsigned int r = (v.u + 0x7fff + ((v.u >> 16) & 1)) >> 16;  // RNE
  return (unsigned short)r;
}
__device__ __forceinline__ float b2f(unsigned short u){
  return __uint_as_float((unsigned)u << 16);
}

__device__ __forceinline__ float wave_sum(float v){
#pragma unroll
  for (int d = 32; d > 0; d >>= 1) v += __shfl_xor(v, d, 64);
  return v;
}

// ---------------- CSR build ----------------

__global__ __launch_bounds__(256) void k_zero_int(int* p, int n){
  int i = blockIdx.x * 256 + threadIdx.x;
  if (i < n) p[i] = 0;
}

__global__ __launch_bounds__(256) void k_deg(const int* __restrict__ ei, int E, int N,
                                             int* __restrict__ deg){
  int e = blockIdx.x * 256 + threadIdx.x;
  int Et = E + N;
  if (e < Et){
    int d = (e < E) ? ei[E + e] : (e - E);
    atomicAdd(&deg[d], 1);
  }
}

__global__ __launch_bounds__(256) void k_scan_local(const int* __restrict__ deg,
                                                    int* __restrict__ offs,
                                                    int* __restrict__ bsum, int n){
  __shared__ int ws4[4];
  int tid = threadIdx.x, lane = tid & 63, wid = tid >> 6;
  int base = blockIdx.x * 1024 + tid * 4;
  int v[4]; int s = 0;
#pragma unroll
  for (int j = 0; j < 4; j++){ v[j] = (base + j < n) ? deg[base + j] : 0; s += v[j]; }
  int x = s;
#pragma unroll
  for (int d = 1; d < 64; d <<= 1){ int t = __shfl_up(x, d, 64); if (lane >= d) x += t; }
  if (lane == 63) ws4[wid] = x;
  __syncthreads();
  int wbase = 0;
  for (int w = 0; w < wid; w++) wbase += ws4[w];
  int run = wbase + x - s;
#pragma unroll
  for (int j = 0; j < 4; j++){
    if (base + j < n) offs[base + j] = run;
    run += v[j];
  }
  if (tid == 0) bsum[blockIdx.x] = ws4[0] + ws4[1] + ws4[2] + ws4[3];
}

__global__ void k_scan_sums(const int* __restrict__ bsum, int* __restrict__ bbase,
                            int* __restrict__ offs, int n, int nb){
  int lane = threadIdx.x;
  int v = (lane < nb) ? bsum[lane] : 0;
  int x = v;
#pragma unroll
  for (int d = 1; d < 64; d <<= 1){ int t = __shfl_up(x, d, 64); if (lane >= d) x += t; }
  if (lane < nb) bbase[lane] = x - v;
  int total = __shfl(x, nb - 1, 64);
  if (lane == 0) offs[n] = total;
}

__global__ __launch_bounds__(256) void k_scan_add(int* __restrict__ offs,
                                                  const int* __restrict__ bbase, int n){
  int i = blockIdx.x * 256 + threadIdx.x;
  if (i < n) offs[i] += bbase[i >> 10];
}

__global__ __launch_bounds__(256) void k_scatter(const int* __restrict__ ei, int E, int N,
                                                 const int* __restrict__ offs,
                                                 int* __restrict__ cursor,
                                                 int* __restrict__ csr){
  int e = blockIdx.x * 256 + threadIdx.x;
  int Et = E + N;
  if (e < Et){
    int d = (e < E) ? ei[E + e] : (e - E);
    int s = (e < E) ? ei[e]     : (e - E);
    int p = atomicAdd(&cursor[d], 1);
    csr[offs[d] + p] = s;
  }
}

// ---------------- merged weight prep + x->bf16 ----------------

__global__ __launch_bounds__(256) void k_prep(const float* __restrict__ W1,
                                              const float* __restrict__ as1,
                                              const float* __restrict__ ad1,
                                              const float* __restrict__ W2,
                                              const float* __restrict__ W3,
                                              const float* __restrict__ x,
                                              __hip_bfloat16* __restrict__ W1rep,
                                              __hip_bfloat16* __restrict__ W2T,
                                              __hip_bfloat16* __restrict__ W3rep,
                                              float* __restrict__ us,
                                              float* __restrict__ ud,
                                              unsigned short* __restrict__ xbf, int N){
  int b = blockIdx.x;
  if (b < 512){
    int id = b * 256 + threadIdx.x;
    int k = id >> 7, n = id & 127;
    W2T[(size_t)n * 1024 + k] = __float2bfloat16(W2[id]);
  } else if (b < 896){
    int id = (b - 512) * 256 + threadIdx.x;
    if (id < 8 * 128 * 96){
      int k = id % 96;
      int rc = id / 96;
      int col = rc & 127, h = rc >> 7;
      float v = (k < 66) ? W1[(size_t)k * 1024 + h * 128 + col] : 0.f;
      W1rep[id] = __float2bfloat16(v);
    }
  } else if (b < 928){
    int id = (b - 896) * 256 + threadIdx.x;
    int k = id & 127, col = id >> 7;
    W3rep[id] = __float2bfloat16(W3[(size_t)k * 64 + col]);
  } else if (b == 928){
    for (int id = threadIdx.x; id < 528; id += 256){
      int c = id >> 3, h = id & 7;
      const float* wrow = W1 + (size_t)c * 1024 + h * 128;
      float s0 = 0.f, s1 = 0.f;
      for (int m = 0; m < 128; m++){
        float w = wrow[m];
        s0 = fmaf(w, as1[h * 128 + m], s0);
        s1 = fmaf(w, ad1[h * 128 + m], s1);
      }
      us[id] = s0; ud[id] = s1;
    }
  } else {
    int id = (b - 929) * 256 + threadIdx.x;
    if (id < N * 68){
      int n = id / 68, c = id - n * 68;
      float v = (c < 66) ? x[(size_t)n * 66 + c] : 0.f;
      xbf[id] = f2bf(v);
    }
  }
}

// ---------------- layer 1 ----------------

// LDS-staged escore (coalesced x reads)
__global__ __launch_bounds__(256) void k_escore1(const float* __restrict__ x,
                                                 const float* __restrict__ us,
                                                 const float* __restrict__ ud,
                                                 float* __restrict__ ssrc,
                                                 float* __restrict__ sdst, int N){
  __shared__ float xs[128 * 66];
  __shared__ float us_s[528], ud_s[528];
  int tid = threadIdx.x;
  int base = blockIdx.x * 128;
  int cnt = min(128, N - base);
  for (int i = tid; i < 528; i += 256){ us_s[i] = us[i]; ud_s[i] = ud[i]; }
  const float* xg = x + (size_t)base * 66;
  int tot = cnt * 66;
  for (int i = tid; i < tot; i += 256) xs[i] = xg[i];
  __syncthreads();
  if (tid >= cnt) return;
  const float* xp = &xs[tid * 66];
  float es[8], ed[8];
#pragma unroll
  for (int h = 0; h < 8; h++){ es[h] = 0.f; ed[h] = 0.f; }
  for (int c2 = 0; c2 < 33; c2++){
    float2 xv = *(const float2*)&xp[c2 * 2];
    int c = c2 * 2;
#pragma unroll
    for (int h = 0; h < 8; h++){
      es[h] = fmaf(xv.x, us_s[c * 8 + h], fmaf(xv.y, us_s[(c + 1) * 8 + h], es[h]));
      ed[h] = fmaf(xv.x, ud_s[c * 8 + h], fmaf(xv.y, ud_s[(c + 1) * 8 + h], ed[h]));
    }
  }
  int n = base + tid;
  *(float4*)&ssrc[(size_t)n * 8]     = (float4){es[0], es[1], es[2], es[3]};
  *(float4*)&ssrc[(size_t)n * 8 + 4] = (float4){es[4], es[5], es[6], es[7]};
  *(float4*)&sdst[(size_t)n * 8]     = (float4){ed[0], ed[1], ed[2], ed[3]};
  *(float4*)&sdst[(size_t)n * 8 + 4] = (float4){ed[4], ed[5], ed[6], ed[7]};
}

// aggregate x (bf16 gather); alpha inline; HEAD-MAJOR Xag[h][n][96]
__global__ __launch_bounds__(256) void k_agg1(const unsigned short* __restrict__ xbf,
                                              const int* __restrict__ offs,
                                              const int* __restrict__ csr,
                                              const float* __restrict__ ssrc,
                                              const float* __restrict__ sdst,
                                              __hip_bfloat16* __restrict__ Xag, int N){
  __shared__ float a_s[4][64][8];
  int tid = threadIdx.x, lane = tid & 63, wid = tid >> 6;
  int n = blockIdx.x * 4 + wid;
  if (n >= N) return;
  int o0 = offs[n], o1 = offs[n + 1];

  float4 sd0 = *(const float4*)&sdst[(size_t)n * 8];
  float4 sd1 = *(const float4*)&sdst[(size_t)n * 8 + 4];

  float acc[8], acc2[8], z[8];
#pragma unroll
  for (int h = 0; h < 8; h++){ acc[h] = 0.f; acc2[h] = 0.f; z[h] = 0.f; }
  int c1 = 64 + lane;

  for (int cb = o0; cb < o1; cb += 64){
    int cnt = min(64, o1 - cb);
    int sreg = (lane < cnt) ? csr[cb + lane] : 0;
    if (lane < cnt){
      float4 a0 = *(const float4*)&ssrc[(size_t)sreg * 8];
      float4 a1 = *(const float4*)&ssrc[(size_t)sreg * 8 + 4];
      float4 w0, w1;
      w0.x = __expf(lrelu(a0.x + sd0.x));
      w0.y = __expf(lrelu(a0.y + sd0.y));
      w0.z = __expf(lrelu(a0.z + sd0.z));
      w0.w = __expf(lrelu(a0.w + sd0.w));
      w1.x = __expf(lrelu(a1.x + sd1.x));
      w1.y = __expf(lrelu(a1.y + sd1.y));
      w1.z = __expf(lrelu(a1.z + sd1.z));
      w1.w = __expf(lrelu(a1.w + sd1.w));
      *(float4*)&a_s[wid][lane][0] = w0;
      *(float4*)&a_s[wid][lane][4] = w1;
    }
    for (int jj = 0; jj < cnt; jj++){
      int s = __shfl(sreg, jj, 64);
      float xv = b2f(xbf[(size_t)s * 68 + lane]);
      float xv2 = (lane < 2) ? b2f(xbf[(size_t)s * 68 + c1]) : 0.f;
      float4 a0 = *(const float4*)&a_s[wid][jj][0];
      float4 a1 = *(const float4*)&a_s[wid][jj][4];
      z[0] += a0.x; z[1] += a0.y; z[2] += a0.z; z[3] += a0.w;
      z[4] += a1.x; z[5] += a1.y; z[6] += a1.z; z[7] += a1.w;
      acc[0] = fmaf(a0.x, xv, acc[0]); acc[1] = fmaf(a0.y, xv, acc[1]);
      acc[2] = fmaf(a0.z, xv, acc[2]); acc[3] = fmaf(a0.w, xv, acc[3]);
      acc[4] = fmaf(a1.x, xv, acc[4]); acc[5] = fmaf(a1.y, xv, acc[5]);
      acc[6] = fmaf(a1.z, xv, acc[6]); acc[7] = fmaf(a1.w, xv, acc[7]);
      if (lane < 2){
        acc2[0] = fmaf(a0.x, xv2, acc2[0]); acc2[1] = fmaf(a0.y, xv2, acc2[1]);
        acc2[2] = fmaf(a0.z, xv2, acc2[2]); acc2[3] = fmaf(a0.w, xv2, acc2[3]);
        acc2[4] = fmaf(a1.x, xv2, acc2[4]); acc2[5] = fmaf(a1.y, xv2, acc2[5]);
        acc2[6] = fmaf(a1.z, xv2, acc2[6]); acc2[7] = fmaf(a1.w, xv2, acc2[7]);
      }
    }
  }

  float zi[8];
#pragma unroll
  for (int h = 0; h < 8; h++) zi[h] = 1.f / (z[h] + 1e-16f);

  size_t slab = (size_t)N * 96;
#pragma unroll
  for (int h = 0; h < 8; h++)
    Xag[(size_t)h * slab + (size_t)n * 96 + lane] = __float2bfloat16(acc[h] * zi[h]);
  if (lane < 32){
    __hip_bfloat16 zero = __float2bfloat16(0.f);
#pragma unroll
    for (int h = 0; h < 8; h++)
      Xag[(size_t)h * slab + (size_t)n * 96 + 64 + lane] =
          (lane < 2) ? __float2bfloat16(acc2[h] * zi[h]) : zero;
  }
}

// ---------------- FUSED layers 1+2 projection, 64-node tiles ----------------
// h2 = (ELU(Xag@W1+b1)) @ W2 ; B never hits global memory.
// Per wave: 32 out-channels (2 tiles) x 64 nodes (4 tiles).

__global__ __launch_bounds__(256) void k_gemm12_mfma(const __hip_bfloat16* __restrict__ Xag,
                                                     const __hip_bfloat16* __restrict__ W1rep,
                                                     const float* __restrict__ b1,
                                                     const __hip_bfloat16* __restrict__ W2T,
                                                     unsigned short* __restrict__ h2, int N){
  __shared__ short Bt[64 * 136];
  int tid = threadIdx.x, lane = tid & 63, w = tid >> 6;
  int r0 = blockIdx.x * 64;
  int wm = w * 32;            // out-channel base (2 tiles per wave)
  int n15 = lane & 15, q = lane >> 4;

  const short* Wg1 = (const short*)W1rep;
  const short* Wg2 = (const short*)W2T;

  int nodes[4];
#pragma unroll
  for (int t = 0; t < 4; t++){
    int nd = r0 + t * 16 + n15;
    nodes[t] = (nd < N) ? nd : (N - 1);
  }

  f32x4 acc2[2][4];
#pragma unroll
  for (int mi = 0; mi < 2; mi++)
#pragma unroll
    for (int ni = 0; ni < 4; ni++) acc2[mi][ni] = (f32x4){0.f, 0.f, 0.f, 0.f};

  for (int h = 0; h < 8; h++){
    // gemm1 partial for head h: acc1[2][4] = W1_h-frag x Xag_h-frag
    f32x4 acc1[2][4];
#pragma unroll
    for (int mi = 0; mi < 2; mi++)
#pragma unroll
      for (int ni = 0; ni < 4; ni++) acc1[mi][ni] = (f32x4){0.f, 0.f, 0.f, 0.f};

    const short* Xh = (const short*)Xag + (size_t)h * N * 96;
#pragma unroll
    for (int ks = 0; ks < 3; ks++){
      int k0 = ks * 32 + q * 8;
      short8 wf[2], xf[4];
#pragma unroll
      for (int mi = 0; mi < 2; mi++)
        wf[mi] = *(const short8*)&Wg1[((size_t)h * 128 + wm + mi * 16 + n15) * 96 + k0];
#pragma unroll
      for (int t = 0; t < 4; t++)
        xf[t] = *(const short8*)&Xh[(size_t)nodes[t] * 96 + k0];
#pragma unroll
      for (int mi = 0; mi < 2; mi++)
#pragma unroll
        for (int ni = 0; ni < 4; ni++)
          acc1[mi][ni] = __builtin_amdgcn_mfma_f32_16x16x32_bf16(wf[mi], xf[ni], acc1[mi][ni], 0, 0, 0);
    }

    __syncthreads();   // prior gemm2 reads of Bt complete
#pragma unroll
    for (int mi = 0; mi < 2; mi++){
      int c0 = wm + mi * 16 + q * 4;
      float4 bb = *(const float4*)&b1[h * 128 + c0];
#pragma unroll
      for (int ni = 0; ni < 4; ni++){
        int nrow = ni * 16 + n15;
        ushort4v o;
        o.x = f2bf(eluf(acc1[mi][ni][0] + bb.x));
        o.y = f2bf(eluf(acc1[mi][ni][1] + bb.y));
        o.z = f2bf(eluf(acc1[mi][ni][2] + bb.z));
        o.w = f2bf(eluf(acc1[mi][ni][3] + bb.w));
        *(ushort4v*)&Bt[nrow * 136 + c0] = o;
      }
    }
    __syncthreads();

    // gemm2 partial: acc2 += W2T[:, h*128:+128]-frag x Bt-frag
#pragma unroll
    for (int ks = 0; ks < 4; ks++){
      int k0 = ks * 32 + q * 8;
      short8 wf[2], xf[4];
#pragma unroll
      for (int mi = 0; mi < 2; mi++)
        wf[mi] = *(const short8*)&Wg2[(size_t)(wm + mi * 16 + n15) * 1024 + h * 128 + k0];
#pragma unroll
      for (int t = 0; t < 4; t++)
        xf[t] = *(const short8*)&Bt[(t * 16 + n15) * 136 + k0];
#pragma unroll
      for (int mi = 0; mi < 2; mi++)
#pragma unroll
        for (int ni = 0; ni < 4; ni++)
          acc2[mi][ni] = __builtin_amdgcn_mfma_f32_16x16x32_bf16(wf[mi], xf[ni], acc2[mi][ni], 0, 0, 0);
    }
  }

  // h2 store (bf16, 8B vectorized)
#pragma unroll
  for (int mi = 0; mi < 2; mi++){
    int c0 = wm + mi * 16 + q * 4;
#pragma unroll
    for (int ni = 0; ni < 4; ni++){
      int node = r0 + ni * 16 + n15;
      if (node < N){
        ushort4v o;
        o.x = f2bf(acc2[mi][ni][0]); o.y = f2bf(acc2[mi][ni][1]);
        o.z = f2bf(acc2[mi][ni][2]); o.w = f2bf(acc2[mi][ni][3]);
        *(ushort4v*)&h2[(size_t)node * 128 + c0] = o;
      }
    }
  }
}

// ---------------- layer 3 GEMM: barrier-free MFMA, bf16 in/out ----------------

__global__ __launch_bounds__(256) void k_gemm3_mfma(const unsigned short* __restrict__ out2,
                                                    const __hip_bfloat16* __restrict__ W3rep,
                                                    unsigned short* __restrict__ h3, int N){
  int tid = threadIdx.x, lane = tid & 63, w = tid >> 6;
  int r0 = blockIdx.x * 256;
  int wn = w * 64;
  int n15 = lane & 15, q = lane >> 4;
  f32x4 acc[4][4];
#pragma unroll
  for (int mi = 0; mi < 4; mi++)
#pragma unroll
    for (int ni = 0; ni < 4; ni++) acc[mi][ni] = (f32x4){0.f, 0.f, 0.f, 0.f};

  const short* Ag = (const short*)out2;
  const short* Wg = (const short*)W3rep;

  int nodes[4];
#pragma unroll
  for (int t = 0; t < 4; t++){
    int nd = r0 + wn + t * 16 + n15;
    nodes[t] = (nd < N) ? nd : (N - 1);
  }

#pragma unroll
  for (int ks = 0; ks < 4; ks++){
    int k0 = ks * 32 + q * 8;
    short8 wf[4], xf[4];
#pragma unroll
    for (int t = 0; t < 4; t++){
      wf[t] = *(const short8*)&Wg[(size_t)(t * 16 + n15) * 128 + k0];
      xf[t] = *(const short8*)&Ag[(size_t)nodes[t] * 128 + k0];
    }
#pragma unroll
    for (int mi = 0; mi < 4; mi++)
#pragma unroll
      for (int ni = 0; ni < 4; ni++)
        acc[mi][ni] = __builtin_amdgcn_mfma_f32_16x16x32_bf16(wf[mi], xf[ni], acc[mi][ni], 0, 0, 0);
  }

#pragma unroll
  for (int mi = 0; mi < 4; mi++){
    int c0 = mi * 16 + q * 4;
#pragma unroll
    for (int ni = 0; ni < 4; ni++){
      int node = r0 + wn + ni * 16 + n15;
      if (node < N){
        ushort4v o;
        o.x = f2bf(acc[mi][ni][0]); o.y = f2bf(acc[mi][ni][1]);
        o.z = f2bf(acc[mi][ni][2]); o.w = f2bf(acc[mi][ni][3]);
        *(ushort4v*)&h3[(size_t)node * 64 + c0] = o;
      }
    }
  }
}

// ---------------- attention dots (bf16 input) + aggregation ----------------

template<int C>
__global__ __launch_bounds__(256) void k_dots(const unsigned short* __restrict__ Hb,
                                              const float* __restrict__ Asrc,
                                              const float* __restrict__ Adst,
                                              float* __restrict__ Ssrc,
                                              float* __restrict__ Sdst, int N){
  int n = blockIdx.x * 256 + threadIdx.x;
  if (n >= N) return;
  const unsigned short* hp = Hb + (size_t)n * C;
  float as_ = 0.f, ad_ = 0.f;
  for (int c8 = 0; c8 < C / 8; c8++){
    ushort8v hv = *(const ushort8v*)&hp[c8 * 8];
    int c = c8 * 8;
#pragma unroll
    for (int j = 0; j < 8; j++){
      float h = b2f(hv[j]);
      as_ = fmaf(h, Asrc[c + j], as_);
      ad_ = fmaf(h, Adst[c + j], ad_);
    }
  }
  Ssrc[n] = as_; Sdst[n] = ad_;
}

template<int C, bool FINAL>
__global__ __launch_bounds__(256) void k_agg(const unsigned short* __restrict__ Hb,
                                             const int* __restrict__ offs,
                                             const int* __restrict__ csr,
                                             const float* __restrict__ Ssrc,
                                             const float* __restrict__ Sdst,
                                             const float* __restrict__ bias,
                                             const float* __restrict__ Wr,
                                             const float* __restrict__ br,
                                             void* __restrict__ OutP, int N){
  int wid = threadIdx.x >> 6, lane = threadIdx.x & 63;
  int n = blockIdx.x * 4 + wid;
  if (n >= N) return;
  int o0 = offs[n], o1 = offs[n + 1];
  float sd = Sdst[n];

  constexpr int CP = C / 64;
  float acc[CP];
#pragma unroll
  for (int r = 0; r < CP; r++) acc[r] = 0.f;
  float z = 0.f;

  for (int j = o0; j < o1; j++){
    int s = csr[j];
    float w = __expf(lrelu(Ssrc[s] + sd));
    z += w;
    const unsigned short* hp = Hb + (size_t)s * C;
#pragma unroll
    for (int r = 0; r < CP; r++) acc[r] = fmaf(w, b2f(hp[lane + r * 64]), acc[r]);
  }
  float iz = 1.f / (z + 1e-16f);

  if (!FINAL){
    unsigned short* Out = (unsigned short*)OutP;
#pragma unroll
    for (int r = 0; r < CP; r++){
      int c = lane + r * 64;
      Out[(size_t)n * C + c] = f2bf(eluf(acc[r] * iz + bias[c]));
    }
  } else {
    float* Out = (float*)OutP;
    float v = eluf(acc[0] * iz + bias[lane]);
    float t = wave_sum(v * Wr[lane]);
    if (lane == 0) Out[n] = 1.f / (1.f + __expf(-(t + br[0])));
  }
}

// ---------------- host launch ----------------

extern "C" void kernel_launch(void* const* d_in, const int* in_sizes, int n_in,
                              void* d_out, int out_size, void* d_ws, size_t ws_size,
                              hipStream_t stream){
  const float* x   = (const float*)d_in[0];
  const int*   ei  = (const int*)  d_in[1];
  const float* W1  = (const float*)d_in[2];
  const float* as1 = (const float*)d_in[3];
  const float* ad1 = (const float*)d_in[4];
  const float* b1  = (const float*)d_in[5];
  const float* W2  = (const float*)d_in[6];
  const float* as2 = (const float*)d_in[7];
  const float* ad2 = (const float*)d_in[8];
  const float* b2  = (const float*)d_in[9];
  const float* W3  = (const float*)d_in[10];
  const float* as3 = (const float*)d_in[11];
  const float* ad3 = (const float*)d_in[12];
  const float* b3  = (const float*)d_in[13];
  const float* Wr  = (const float*)d_in[14];
  const float* br  = (const float*)d_in[15];

  const int N  = in_sizes[0] / 66;
  const int E  = in_sizes[1] / 2;
  const int Et = E + N;
  const int NB = (N + 1023) / 1024;
  const int NT = (N + 255) / 256;
  const int NE = (N + 127) / 128;
  const int NXB = (N * 68 + 255) / 256;

  size_t off = 0;
  auto take = [&](size_t bytes) -> void* {
    void* p = (char*)d_ws + off;
    off = (off + bytes + 255) & ~(size_t)255;
    return p;
  };
  int*   deg    = (int*)take((size_t)2 * N * 4);
  int*   cursor = deg + N;
  int*   offs   = (int*)take((size_t)(N + 1) * 4);
  int*   csr    = (int*)take((size_t)Et * 4);
  int*   bsum   = (int*)take(64 * 4);
  int*   bbase  = (int*)take(64 * 4);
  float* ssrc   = (float*)take((size_t)N * 8 * 4);
  float* sdst   = (float*)take((size_t)N * 8 * 4);
  float* us     = (float*)take(528 * 4);
  float* ud     = (float*)take(528 * 4);
  __hip_bfloat16* W2T   = (__hip_bfloat16*)take((size_t)128 * 1024 * 2);
  __hip_bfloat16* W1rep = (__hip_bfloat16*)take((size_t)8 * 128 * 96 * 2);
  __hip_bfloat16* W3rep = (__hip_bfloat16*)take((size_t)64 * 128 * 2);
  unsigned short* xbf   = (unsigned short*)take((size_t)N * 68 * 2);
  // Xag lives through k_gemm12; out2/h3 overlay it afterward
  size_t xag_bytes = (size_t)N * 8 * 96 * 2;
  void*  U = take(xag_bytes);
  __hip_bfloat16* Xag = (__hip_bfloat16*)U;
  unsigned short* out2 = (unsigned short*)U;
  unsigned short* h3   = (unsigned short*)((char*)U + (size_t)N * 128 * 2);
  unsigned short* h2   = (unsigned short*)take((size_t)N * 128 * 2);
  (void)ws_size; (void)n_in; (void)out_size;

  // CSR build
  k_zero_int<<<dim3((2 * N + 255) / 256), dim3(256), 0, stream>>>(deg, 2 * N);
  k_deg<<<dim3((Et + 255) / 256), dim3(256), 0, stream>>>(ei, E, N, deg);
  k_scan_local<<<dim3(NB), dim3(256), 0, stream>>>(deg, offs, bsum, N);
  k_scan_sums<<<dim3(1), dim3(64), 0, stream>>>(bsum, bbase, offs, N, NB);
  k_scan_add<<<dim3((N + 255) / 256), dim3(256), 0, stream>>>(offs, bbase, N);
  k_scatter<<<dim3((Et + 255) / 256), dim3(256), 0, stream>>>(ei, E, N, offs, cursor, csr);

  // merged weight prep + x->bf16
  k_prep<<<dim3(929 + NXB), dim3(256), 0, stream>>>(W1, as1, ad1, W2, W3, x,
                                                    W1rep, W2T, W3rep, us, ud, xbf, N);

  // layer 1
  k_escore1<<<dim3(NE), dim3(256), 0, stream>>>(x, us, ud, ssrc, sdst, N);
  k_agg1<<<dim3((N + 3) / 4), dim3(256), 0, stream>>>(xbf, offs, csr, ssrc, sdst, Xag, N);

  // fused layers 1+2 projection (64-node tiles)
  k_gemm12_mfma<<<dim3((N + 63) / 64), dim3(256), 0, stream>>>(
      Xag, W1rep, b1, W2T, h2, N);

  // layer 2 attention
  k_dots<128><<<dim3(NT), dim3(256), 0, stream>>>(h2, as2, ad2, ssrc, sdst, N);
  k_agg<128, false><<<dim3((N + 3) / 4), dim3(256), 0, stream>>>(
      h2, offs, csr, ssrc, sdst, b2, nullptr, nullptr, out2, N);

  // layer 3
  k_gemm3_mfma<<<dim3((N + 255) / 256), dim3(256), 0, stream>>>(out2, W3rep, h3, N);
  k_dots<64><<<dim3(NT), dim3(256), 0, stream>>>(h3, as3, ad3, ssrc, sdst, N);
  k_agg<64, true><<<dim3((N + 3) / 4), dim3(256), 0, stream>>>(
      h3, offs, csr, ssrc, sdst, b3, Wr, br, d_out, N);
}

// Round 21
// 346.084 us; speedup vs baseline: 1.0386x; 1.0386x over previous
//
#include <hip/hip_runtime.h>
#include <hip/hip_bf16.h>
#include <cstdint>
#include <cstddef>

#define NEG_SLOPE 0.2f

typedef short short8 __attribute__((ext_vector_type(8)));
typedef float f32x4 __attribute__((ext_vector_type(4)));
typedef unsigned short ushort4v __attribute__((ext_vector_type(4)));
typedef unsigned short ushort8v __attribute__((ext_vector_type(8)));

__device__ __forceinline__ float lrelu(float x){ return x > 0.f ? x : NEG_SLOPE * x; }
__device__ __forceinline__ float eluf(float x){ return x > 0.f ? x : __expf(x) - 1.f; }

__device__ __forceinline__ unsigned short f2bf(float f){
  union { float f; unsigned int u; } v; v.f = f;
  unsigned int r = (v.u + 0x7fff + ((v.u >> 16) & 1)) >> 16;  // RNE
  return (unsigned short)r;
}
__device__ __forceinline__ float b2f(unsigned short u){
  return __uint_as_float((unsigned)u << 16);
}

__device__ __forceinline__ float wave_sum(float v){
#pragma unroll
  for (int d = 32; d > 0; d >>= 1) v += __shfl_xor(v, d, 64);
  return v;
}

// ---------------- CSR build ----------------

__global__ __launch_bounds__(256) void k_zero_int(int* p, int n){
  int i = blockIdx.x * 256 + threadIdx.x;
  if (i < n) p[i] = 0;
}

__global__ __launch_bounds__(256) void k_deg(const int* __restrict__ ei, int E, int N,
                                             int* __restrict__ deg){
  int e = blockIdx.x * 256 + threadIdx.x;
  int Et = E + N;
  if (e < Et){
    int d = (e < E) ? ei[E + e] : (e - E);
    atomicAdd(&deg[d], 1);
  }
}

__global__ __launch_bounds__(256) void k_scan_local(const int* __restrict__ deg,
                                                    int* __restrict__ offs,
                                                    int* __restrict__ bsum, int n){
  __shared__ int ws4[4];
  int tid = threadIdx.x, lane = tid & 63, wid = tid >> 6;
  int base = blockIdx.x * 1024 + tid * 4;
  int v[4]; int s = 0;
#pragma unroll
  for (int j = 0; j < 4; j++){ v[j] = (base + j < n) ? deg[base + j] : 0; s += v[j]; }
  int x = s;
#pragma unroll
  for (int d = 1; d < 64; d <<= 1){ int t = __shfl_up(x, d, 64); if (lane >= d) x += t; }
  if (lane == 63) ws4[wid] = x;
  __syncthreads();
  int wbase = 0;
  for (int w = 0; w < wid; w++) wbase += ws4[w];
  int run = wbase + x - s;
#pragma unroll
  for (int j = 0; j < 4; j++){
    if (base + j < n) offs[base + j] = run;
    run += v[j];
  }
  if (tid == 0) bsum[blockIdx.x] = ws4[0] + ws4[1] + ws4[2] + ws4[3];
}

__global__ void k_scan_sums(const int* __restrict__ bsum, int* __restrict__ bbase,
                            int* __restrict__ offs, int n, int nb){
  int lane = threadIdx.x;
  int v = (lane < nb) ? bsum[lane] : 0;
  int x = v;
#pragma unroll
  for (int d = 1; d < 64; d <<= 1){ int t = __shfl_up(x, d, 64); if (lane >= d) x += t; }
  if (lane < nb) bbase[lane] = x - v;
  int total = __shfl(x, nb - 1, 64);
  if (lane == 0) offs[n] = total;
}

__global__ __launch_bounds__(256) void k_scan_add(int* __restrict__ offs,
                                                  const int* __restrict__ bbase, int n){
  int i = blockIdx.x * 256 + threadIdx.x;
  if (i < n) offs[i] += bbase[i >> 10];
}

__global__ __launch_bounds__(256) void k_scatter(const int* __restrict__ ei, int E, int N,
                                                 const int* __restrict__ offs,
                                                 int* __restrict__ cursor,
                                                 int* __restrict__ csr){
  int e = blockIdx.x * 256 + threadIdx.x;
  int Et = E + N;
  if (e < Et){
    int d = (e < E) ? ei[E + e] : (e - E);
    int s = (e < E) ? ei[e]     : (e - E);
    int p = atomicAdd(&cursor[d], 1);
    csr[offs[d] + p] = s;
  }
}

// ---------------- merged weight prep + x->bf16 ----------------
// blocks [0,512): W2T; [512,896): W1rep; [896,928): W3rep; 928: uvec1; [929,...): x_bf

__global__ __launch_bounds__(256) void k_prep(const float* __restrict__ W1,
                                              const float* __restrict__ as1,
                                              const float* __restrict__ ad1,
                                              const float* __restrict__ W2,
                                              const float* __restrict__ W3,
                                              const float* __restrict__ x,
                                              __hip_bfloat16* __restrict__ W1rep,
                                              __hip_bfloat16* __restrict__ W2T,
                                              __hip_bfloat16* __restrict__ W3rep,
                                              float* __restrict__ us,
                                              float* __restrict__ ud,
                                              unsigned short* __restrict__ xbf, int N){
  int b = blockIdx.x;
  if (b < 512){
    int id = b * 256 + threadIdx.x;
    int k = id >> 7, n = id & 127;
    W2T[(size_t)n * 1024 + k] = __float2bfloat16(W2[id]);
  } else if (b < 896){
    int id = (b - 512) * 256 + threadIdx.x;
    if (id < 8 * 128 * 96){
      int k = id % 96;
      int rc = id / 96;
      int col = rc & 127, h = rc >> 7;
      float v = (k < 66) ? W1[(size_t)k * 1024 + h * 128 + col] : 0.f;
      W1rep[id] = __float2bfloat16(v);
    }
  } else if (b < 928){
    int id = (b - 896) * 256 + threadIdx.x;
    int k = id & 127, col = id >> 7;
    W3rep[id] = __float2bfloat16(W3[(size_t)k * 64 + col]);
  } else if (b == 928){
    for (int id = threadIdx.x; id < 528; id += 256){
      int c = id >> 3, h = id & 7;
      const float* wrow = W1 + (size_t)c * 1024 + h * 128;
      float s0 = 0.f, s1 = 0.f;
      for (int m = 0; m < 128; m++){
        float w = wrow[m];
        s0 = fmaf(w, as1[h * 128 + m], s0);
        s1 = fmaf(w, ad1[h * 128 + m], s1);
      }
      us[id] = s0; ud[id] = s1;
    }
  } else {
    // x -> bf16, padded row stride 68 (cols 66,67 zeroed)
    int id = (b - 929) * 256 + threadIdx.x;
    if (id < N * 68){
      int n = id / 68, c = id - n * 68;
      float v = (c < 66) ? x[(size_t)n * 66 + c] : 0.f;
      xbf[id] = f2bf(v);
    }
  }
}

// ---------------- layer 1 ----------------

// LDS-staged escore: block stages 128 contiguous x-rows (coalesced) + us/ud,
// then 128 threads compute their node's 16 dots from LDS (2-way bank = free)
__global__ __launch_bounds__(256) void k_escore1(const float* __restrict__ x,
                                                 const float* __restrict__ us,
                                                 const float* __restrict__ ud,
                                                 float* __restrict__ ssrc,
                                                 float* __restrict__ sdst, int N){
  __shared__ float xs[128 * 66];
  __shared__ float us_s[528], ud_s[528];
  int tid = threadIdx.x;
  int base = blockIdx.x * 128;
  int cnt = min(128, N - base);
  for (int i = tid; i < 528; i += 256){ us_s[i] = us[i]; ud_s[i] = ud[i]; }
  const float* xg = x + (size_t)base * 66;
  int tot = cnt * 66;
  for (int i = tid; i < tot; i += 256) xs[i] = xg[i];
  __syncthreads();
  if (tid >= cnt) return;
  const float* xp = &xs[tid * 66];
  float es[8], ed[8];
#pragma unroll
  for (int h = 0; h < 8; h++){ es[h] = 0.f; ed[h] = 0.f; }
  for (int c2 = 0; c2 < 33; c2++){
    float2 xv = *(const float2*)&xp[c2 * 2];
    int c = c2 * 2;
#pragma unroll
    for (int h = 0; h < 8; h++){
      es[h] = fmaf(xv.x, us_s[c * 8 + h], fmaf(xv.y, us_s[(c + 1) * 8 + h], es[h]));
      ed[h] = fmaf(xv.x, ud_s[c * 8 + h], fmaf(xv.y, ud_s[(c + 1) * 8 + h], ed[h]));
    }
  }
  int n = base + tid;
  *(float4*)&ssrc[(size_t)n * 8]     = (float4){es[0], es[1], es[2], es[3]};
  *(float4*)&ssrc[(size_t)n * 8 + 4] = (float4){es[4], es[5], es[6], es[7]};
  *(float4*)&sdst[(size_t)n * 8]     = (float4){ed[0], ed[1], ed[2], ed[3]};
  *(float4*)&sdst[(size_t)n * 8 + 4] = (float4){ed[4], ed[5], ed[6], ed[7]};
}

// aggregate x (bf16 gather); alpha computed INLINE during LDS staging;
// z accumulated in the broadcast loop. HEAD-MAJOR out: Xag[h][n][96] bf16.
__global__ __launch_bounds__(256) void k_agg1(const unsigned short* __restrict__ xbf,
                                              const int* __restrict__ offs,
                                              const int* __restrict__ csr,
                                              const float* __restrict__ ssrc,
                                              const float* __restrict__ sdst,
                                              __hip_bfloat16* __restrict__ Xag, int N){
  __shared__ float a_s[4][64][8];
  int tid = threadIdx.x, lane = tid & 63, wid = tid >> 6;
  int n = blockIdx.x * 4 + wid;
  if (n >= N) return;
  int o0 = offs[n], o1 = offs[n + 1];

  float4 sd0 = *(const float4*)&sdst[(size_t)n * 8];
  float4 sd1 = *(const float4*)&sdst[(size_t)n * 8 + 4];

  float acc[8], acc2[8], z[8];
#pragma unroll
  for (int h = 0; h < 8; h++){ acc[h] = 0.f; acc2[h] = 0.f; z[h] = 0.f; }
  int c1 = 64 + lane;  // lanes 0,1 only

  for (int cb = o0; cb < o1; cb += 64){
    int cnt = min(64, o1 - cb);
    int sreg = (lane < cnt) ? csr[cb + lane] : 0;
    if (lane < cnt){
      float4 a0 = *(const float4*)&ssrc[(size_t)sreg * 8];
      float4 a1 = *(const float4*)&ssrc[(size_t)sreg * 8 + 4];
      float4 w0, w1;
      w0.x = __expf(lrelu(a0.x + sd0.x));
      w0.y = __expf(lrelu(a0.y + sd0.y));
      w0.z = __expf(lrelu(a0.z + sd0.z));
      w0.w = __expf(lrelu(a0.w + sd0.w));
      w1.x = __expf(lrelu(a1.x + sd1.x));
      w1.y = __expf(lrelu(a1.y + sd1.y));
      w1.z = __expf(lrelu(a1.z + sd1.z));
      w1.w = __expf(lrelu(a1.w + sd1.w));
      *(float4*)&a_s[wid][lane][0] = w0;
      *(float4*)&a_s[wid][lane][4] = w1;
    }
    for (int jj = 0; jj < cnt; jj++){
      int s = __shfl(sreg, jj, 64);
      float xv = b2f(xbf[(size_t)s * 68 + lane]);
      float xv2 = (lane < 2) ? b2f(xbf[(size_t)s * 68 + c1]) : 0.f;
      float4 a0 = *(const float4*)&a_s[wid][jj][0];
      float4 a1 = *(const float4*)&a_s[wid][jj][4];
      z[0] += a0.x; z[1] += a0.y; z[2] += a0.z; z[3] += a0.w;
      z[4] += a1.x; z[5] += a1.y; z[6] += a1.z; z[7] += a1.w;
      acc[0] = fmaf(a0.x, xv, acc[0]); acc[1] = fmaf(a0.y, xv, acc[1]);
      acc[2] = fmaf(a0.z, xv, acc[2]); acc[3] = fmaf(a0.w, xv, acc[3]);
      acc[4] = fmaf(a1.x, xv, acc[4]); acc[5] = fmaf(a1.y, xv, acc[5]);
      acc[6] = fmaf(a1.z, xv, acc[6]); acc[7] = fmaf(a1.w, xv, acc[7]);
      if (lane < 2){
        acc2[0] = fmaf(a0.x, xv2, acc2[0]); acc2[1] = fmaf(a0.y, xv2, acc2[1]);
        acc2[2] = fmaf(a0.z, xv2, acc2[2]); acc2[3] = fmaf(a0.w, xv2, acc2[3]);
        acc2[4] = fmaf(a1.x, xv2, acc2[4]); acc2[5] = fmaf(a1.y, xv2, acc2[5]);
        acc2[6] = fmaf(a1.z, xv2, acc2[6]); acc2[7] = fmaf(a1.w, xv2, acc2[7]);
      }
    }
  }

  float zi[8];
#pragma unroll
  for (int h = 0; h < 8; h++) zi[h] = 1.f / (z[h] + 1e-16f);

  size_t slab = (size_t)N * 96;
#pragma unroll
  for (int h = 0; h < 8; h++)
    Xag[(size_t)h * slab + (size_t)n * 96 + lane] = __float2bfloat16(acc[h] * zi[h]);
  if (lane < 32){
    __hip_bfloat16 zero = __float2bfloat16(0.f);
#pragma unroll
    for (int h = 0; h < 8; h++)
      Xag[(size_t)h * slab + (size_t)n * 96 + 64 + lane] =
          (lane < 2) ? __float2bfloat16(acc2[h] * zi[h]) : zero;
  }
}

// layer-1 projection: barrier-free MFMA (head-major Xag) + LDS-transposed epilogue
__global__ __launch_bounds__(256) void k_gemm1_mfma(const __hip_bfloat16* __restrict__ Xag,
                                                    const __hip_bfloat16* __restrict__ W1rep,
                                                    const float* __restrict__ b1,
                                                    __hip_bfloat16* __restrict__ B, int N){
  __shared__ short ob[128 * 136];
  int tid = threadIdx.x, lane = tid & 63, w = tid >> 6;
  int r0 = blockIdx.x * 128;
  int h  = blockIdx.y;
  int wm = (w >> 1) * 64;
  int wn = (w & 1) * 64;
  int n15 = lane & 15, q = lane >> 4;
  f32x4 acc[4][4];
#pragma unroll
  for (int mi = 0; mi < 4; mi++)
#pragma unroll
    for (int ni = 0; ni < 4; ni++) acc[mi][ni] = (f32x4){0.f, 0.f, 0.f, 0.f};

  const short* Xh = (const short*)Xag + (size_t)h * N * 96;
  const short* Wg = (const short*)W1rep;

  int nodes[4];
#pragma unroll
  for (int t = 0; t < 4; t++){
    int nd = r0 + wn + t * 16 + n15;
    nodes[t] = (nd < N) ? nd : (N - 1);
  }

#pragma unroll
  for (int ks = 0; ks < 3; ks++){
    int k0 = ks * 32 + q * 8;
    short8 wf[4], xf[4];
#pragma unroll
    for (int t = 0; t < 4; t++){
      wf[t] = *(const short8*)&Wg[((size_t)h * 128 + wm + t * 16 + n15) * 96 + k0];
      xf[t] = *(const short8*)&Xh[(size_t)nodes[t] * 96 + k0];
    }
#pragma unroll
    for (int mi = 0; mi < 4; mi++)
#pragma unroll
      for (int ni = 0; ni < 4; ni++)
        acc[mi][ni] = __builtin_amdgcn_mfma_f32_16x16x32_bf16(wf[mi], xf[ni], acc[mi][ni], 0, 0, 0);
  }

#pragma unroll
  for (int mi = 0; mi < 4; mi++){
    int c0 = wm + mi * 16 + q * 4;
    float4 bb = *(const float4*)&b1[h * 128 + c0];
#pragma unroll
    for (int ni = 0; ni < 4; ni++){
      int nrow = wn + ni * 16 + n15;
      ushort4v o;
      o.x = f2bf(eluf(acc[mi][ni][0] + bb.x));
      o.y = f2bf(eluf(acc[mi][ni][1] + bb.y));
      o.z = f2bf(eluf(acc[mi][ni][2] + bb.z));
      o.w = f2bf(eluf(acc[mi][ni][3] + bb.w));
      *(ushort4v*)&ob[nrow * 136 + c0] = o;
    }
  }
  __syncthreads();

#pragma unroll
  for (int p = 0; p < 8; p++){
    int c = p * 256 + tid;
    int row = c >> 4, ch = c & 15;
    int node = r0 + row;
    if (node < N){
      short8 v = *(const short8*)&ob[row * 136 + ch * 8];
      *(short8*)((unsigned short*)B + (size_t)node * 1024 + h * 128 + ch * 8) = v;
    }
  }
}

// ---------------- layer 2 GEMM: LDS-staged, operand-swapped, bf16 out ----------------

__global__ __launch_bounds__(256) void k_gemm2_mfma(const __hip_bfloat16* __restrict__ Abf,
                                                    const __hip_bfloat16* __restrict__ W2T,
                                                    unsigned short* __restrict__ h2, int N){
  __shared__ short As[128 * 32];
  __shared__ short Ws[128 * 32];
  int tid = threadIdx.x, lane = tid & 63, w = tid >> 6;
  int r0 = blockIdx.x * 128;
  int wm = (w >> 1) * 64;
  int wn = (w & 1) * 64;
  f32x4 acc[4][4];
#pragma unroll
  for (int mi = 0; mi < 4; mi++)
#pragma unroll
    for (int ni = 0; ni < 4; ni++) acc[mi][ni] = (f32x4){0.f, 0.f, 0.f, 0.f};

  const short* Ag = (const short*)Abf;
  const short* Bg = (const short*)W2T;

  for (int kt = 0; kt < 1024; kt += 32){
    __syncthreads();
#pragma unroll
    for (int p = 0; p < 2; p++){
      int i = p * 256 + tid;
      int row = i >> 2, c = i & 3;
      int rg = r0 + row; if (rg > N - 1) rg = N - 1;
      const short* gp = Ag + (size_t)rg * 1024 + kt + c * 8;
      __builtin_amdgcn_global_load_lds((const __attribute__((address_space(1))) void*)gp,
                                       (__attribute__((address_space(3))) void*)&As[i * 8],
                                       16, 0, 0);
      const short* gq = Bg + (size_t)row * 1024 + kt + c * 8;
      __builtin_amdgcn_global_load_lds((const __attribute__((address_space(1))) void*)gq,
                                       (__attribute__((address_space(3))) void*)&Ws[i * 8],
                                       16, 0, 0);
    }
    __syncthreads();
    int ko = (lane >> 4) * 8;
    short8 wf[4], xf[4];
#pragma unroll
    for (int t = 0; t < 4; t++){
      wf[t] = *(const short8*)&Ws[(wm + t * 16 + (lane & 15)) * 32 + ko];
      xf[t] = *(const short8*)&As[(wn + t * 16 + (lane & 15)) * 32 + ko];
    }
#pragma unroll
    for (int mi = 0; mi < 4; mi++)
#pragma unroll
      for (int ni = 0; ni < 4; ni++)
        acc[mi][ni] = __builtin_amdgcn_mfma_f32_16x16x32_bf16(wf[mi], xf[ni], acc[mi][ni], 0, 0, 0);
  }

  int n15 = lane & 15, q = lane >> 4;
#pragma unroll
  for (int mi = 0; mi < 4; mi++){
    int c0 = wm + mi * 16 + q * 4;
#pragma unroll
    for (int ni = 0; ni < 4; ni++){
      int node = r0 + wn + ni * 16 + n15;
      if (node < N){
        ushort4v o;
        o.x = f2bf(acc[mi][ni][0]); o.y = f2bf(acc[mi][ni][1]);
        o.z = f2bf(acc[mi][ni][2]); o.w = f2bf(acc[mi][ni][3]);
        *(ushort4v*)&h2[(size_t)node * 128 + c0] = o;
      }
    }
  }
}

// ---------------- layer 3 GEMM: barrier-free MFMA, bf16 in/out ----------------

__global__ __launch_bounds__(256) void k_gemm3_mfma(const unsigned short* __restrict__ out2,
                                                    const __hip_bfloat16* __restrict__ W3rep,
                                                    unsigned short* __restrict__ h3, int N){
  int tid = threadIdx.x, lane = tid & 63, w = tid >> 6;
  int r0 = blockIdx.x * 256;
  int wn = w * 64;
  int n15 = lane & 15, q = lane >> 4;
  f32x4 acc[4][4];
#pragma unroll
  for (int mi = 0; mi < 4; mi++)
#pragma unroll
    for (int ni = 0; ni < 4; ni++) acc[mi][ni] = (f32x4){0.f, 0.f, 0.f, 0.f};

  const short* Ag = (const short*)out2;
  const short* Wg = (const short*)W3rep;

  int nodes[4];
#pragma unroll
  for (int t = 0; t < 4; t++){
    int nd = r0 + wn + t * 16 + n15;
    nodes[t] = (nd < N) ? nd : (N - 1);
  }

#pragma unroll
  for (int ks = 0; ks < 4; ks++){
    int k0 = ks * 32 + q * 8;
    short8 wf[4], xf[4];
#pragma unroll
    for (int t = 0; t < 4; t++){
      wf[t] = *(const short8*)&Wg[(size_t)(t * 16 + n15) * 128 + k0];
      xf[t] = *(const short8*)&Ag[(size_t)nodes[t] * 128 + k0];
    }
#pragma unroll
    for (int mi = 0; mi < 4; mi++)
#pragma unroll
      for (int ni = 0; ni < 4; ni++)
        acc[mi][ni] = __builtin_amdgcn_mfma_f32_16x16x32_bf16(wf[mi], xf[ni], acc[mi][ni], 0, 0, 0);
  }

#pragma unroll
  for (int mi = 0; mi < 4; mi++){
    int c0 = mi * 16 + q * 4;
#pragma unroll
    for (int ni = 0; ni < 4; ni++){
      int node = r0 + wn + ni * 16 + n15;
      if (node < N){
        ushort4v o;
        o.x = f2bf(acc[mi][ni][0]); o.y = f2bf(acc[mi][ni][1]);
        o.z = f2bf(acc[mi][ni][2]); o.w = f2bf(acc[mi][ni][3]);
        *(ushort4v*)&h3[(size_t)node * 64 + c0] = o;
      }
    }
  }
}

// ---------------- attention dots (bf16 input) + aggregation ----------------

template<int C>
__global__ __launch_bounds__(256) void k_dots(const unsigned short* __restrict__ Hb,
                                              const float* __restrict__ Asrc,
                                              const float* __restrict__ Adst,
                                              float* __restrict__ Ssrc,
                                              float* __restrict__ Sdst, int N){
  int n = blockIdx.x * 256 + threadIdx.x;
  if (n >= N) return;
  const unsigned short* hp = Hb + (size_t)n * C;
  float as_ = 0.f, ad_ = 0.f;
  for (int c8 = 0; c8 < C / 8; c8++){
    ushort8v hv = *(const ushort8v*)&hp[c8 * 8];
    int c = c8 * 8;
#pragma unroll
    for (int j = 0; j < 8; j++){
      float h = b2f(hv[j]);
      as_ = fmaf(h, Asrc[c + j], as_);
      ad_ = fmaf(h, Adst[c + j], ad_);
    }
  }
  Ssrc[n] = as_; Sdst[n] = ad_;
}

// z folded in: acc unnormalized + z in same loop, normalize at end
template<int C, bool FINAL>
__global__ __launch_bounds__(256) void k_agg(const unsigned short* __restrict__ Hb,
                                             const int* __restrict__ offs,
                                             const int* __restrict__ csr,
                                             const float* __restrict__ Ssrc,
                                             const float* __restrict__ Sdst,
                                             const float* __restrict__ bias,
                                             const float* __restrict__ Wr,
                                             const float* __restrict__ br,
                                             void* __restrict__ OutP, int N){
  int wid = threadIdx.x >> 6, lane = threadIdx.x & 63;
  int n = blockIdx.x * 4 + wid;
  if (n >= N) return;
  int o0 = offs[n], o1 = offs[n + 1];
  float sd = Sdst[n];

  constexpr int CP = C / 64;
  float acc[CP];
#pragma unroll
  for (int r = 0; r < CP; r++) acc[r] = 0.f;
  float z = 0.f;

  for (int j = o0; j < o1; j++){
    int s = csr[j];
    float w = __expf(lrelu(Ssrc[s] + sd));
    z += w;
    const unsigned short* hp = Hb + (size_t)s * C;
#pragma unroll
    for (int r = 0; r < CP; r++) acc[r] = fmaf(w, b2f(hp[lane + r * 64]), acc[r]);
  }
  float iz = 1.f / (z + 1e-16f);

  if (!FINAL){
    unsigned short* Out = (unsigned short*)OutP;
#pragma unroll
    for (int r = 0; r < CP; r++){
      int c = lane + r * 64;
      Out[(size_t)n * C + c] = f2bf(eluf(acc[r] * iz + bias[c]));
    }
  } else {
    float* Out = (float*)OutP;
    float v = eluf(acc[0] * iz + bias[lane]);
    float t = wave_sum(v * Wr[lane]);
    if (lane == 0) Out[n] = 1.f / (1.f + __expf(-(t + br[0])));
  }
}

// ---------------- host launch ----------------

extern "C" void kernel_launch(void* const* d_in, const int* in_sizes, int n_in,
                              void* d_out, int out_size, void* d_ws, size_t ws_size,
                              hipStream_t stream){
  const float* x   = (const float*)d_in[0];
  const int*   ei  = (const int*)  d_in[1];
  const float* W1  = (const float*)d_in[2];
  const float* as1 = (const float*)d_in[3];
  const float* ad1 = (const float*)d_in[4];
  const float* b1  = (const float*)d_in[5];
  const float* W2  = (const float*)d_in[6];
  const float* as2 = (const float*)d_in[7];
  const float* ad2 = (const float*)d_in[8];
  const float* b2  = (const float*)d_in[9];
  const float* W3  = (const float*)d_in[10];
  const float* as3 = (const float*)d_in[11];
  const float* ad3 = (const float*)d_in[12];
  const float* b3  = (const float*)d_in[13];
  const float* Wr  = (const float*)d_in[14];
  const float* br  = (const float*)d_in[15];

  const int N  = in_sizes[0] / 66;
  const int E  = in_sizes[1] / 2;
  const int Et = E + N;
  const int NB = (N + 1023) / 1024;
  const int NT = (N + 255) / 256;
  const int NE = (N + 127) / 128;   // escore blocks (128 nodes each)
  const int NXB = (N * 68 + 255) / 256;

  size_t off = 0;
  auto take = [&](size_t bytes) -> void* {
    void* p = (char*)d_ws + off;
    off = (off + bytes + 255) & ~(size_t)255;
    return p;
  };
  int*   deg    = (int*)take((size_t)2 * N * 4);
  int*   cursor = deg + N;
  int*   offs   = (int*)take((size_t)(N + 1) * 4);
  int*   csr    = (int*)take((size_t)Et * 4);
  int*   bsum   = (int*)take(64 * 4);
  int*   bbase  = (int*)take(64 * 4);
  float* ssrc   = (float*)take((size_t)N * 8 * 4);
  float* sdst   = (float*)take((size_t)N * 8 * 4);
  float* us     = (float*)take(528 * 4);
  float* ud     = (float*)take(528 * 4);
  __hip_bfloat16* W2T   = (__hip_bfloat16*)take((size_t)128 * 1024 * 2);
  __hip_bfloat16* W1rep = (__hip_bfloat16*)take((size_t)8 * 128 * 96 * 2);
  __hip_bfloat16* W3rep = (__hip_bfloat16*)take((size_t)64 * 128 * 2);
  unsigned short* xbf   = (unsigned short*)take((size_t)N * 68 * 2);
  size_t xag_bytes = (size_t)N * 8 * 96 * 2;
  void*  U = take(xag_bytes);
  __hip_bfloat16* Xag = (__hip_bfloat16*)U;
  unsigned short* h2   = (unsigned short*)U;
  unsigned short* out2 = (unsigned short*)((char*)U + (size_t)N * 128 * 2);
  unsigned short* h3   = h2;
  __hip_bfloat16* B = (__hip_bfloat16*)take((size_t)N * 1024 * 2);
  (void)ws_size; (void)n_in; (void)out_size;

  // CSR build
  k_zero_int<<<dim3((2 * N + 255) / 256), dim3(256), 0, stream>>>(deg, 2 * N);
  k_deg<<<dim3((Et + 255) / 256), dim3(256), 0, stream>>>(ei, E, N, deg);
  k_scan_local<<<dim3(NB), dim3(256), 0, stream>>>(deg, offs, bsum, N);
  k_scan_sums<<<dim3(1), dim3(64), 0, stream>>>(bsum, bbase, offs, N, NB);
  k_scan_add<<<dim3((N + 255) / 256), dim3(256), 0, stream>>>(offs, bbase, N);
  k_scatter<<<dim3((Et + 255) / 256), dim3(256), 0, stream>>>(ei, E, N, offs, cursor, csr);

  // merged weight prep + x->bf16
  k_prep<<<dim3(929 + NXB), dim3(256), 0, stream>>>(W1, as1, ad1, W2, W3, x,
                                                    W1rep, W2T, W3rep, us, ud, xbf, N);

  // layer 1
  k_escore1<<<dim3(NE), dim3(256), 0, stream>>>(x, us, ud, ssrc, sdst, N);
  k_agg1<<<dim3((N + 3) / 4), dim3(256), 0, stream>>>(xbf, offs, csr, ssrc, sdst, Xag, N);
  k_gemm1_mfma<<<dim3((N + 127) / 128, 8), dim3(256), 0, stream>>>(Xag, W1rep, b1, B, N);

  // layer 2
  k_gemm2_mfma<<<dim3((N + 127) / 128), dim3(256), 0, stream>>>(B, W2T, h2, N);
  k_dots<128><<<dim3(NT), dim3(256), 0, stream>>>(h2, as2, ad2, ssrc, sdst, N);
  k_agg<128, false><<<dim3((N + 3) / 4), dim3(256), 0, stream>>>(
      h2, offs, csr, ssrc, sdst, b2, nullptr, nullptr, out2, N);

  // layer 3
  k_gemm3_mfma<<<dim3((N + 255) / 256), dim3(256), 0, stream>>>(out2, W3rep, h3, N);
  k_dots<64><<<dim3(NT), dim3(256), 0, stream>>>(h3, as3, ad3, ssrc, sdst, N);
  k_agg<64, true><<<dim3((N + 3) / 4), dim3(256), 0, stream>>>(
      h3, offs, csr, ssrc, sdst, b3, Wr, br, d_out, N);
}